// Round 14
// baseline (5877.546 us; speedup 1.0000x reference)
//
#include <hip/hip_runtime.h>

#define Bv 32
#define Sv 256
#define Iv 256
#define Cv 512
#define Nv 1024
#define Vv 64
#define Ov 256
#define NBLK 256
#define NTHR 512

// ---- ws layout (int indices) ----
// sync region: host-memset each launch; sc1(agent)-only atomics/spins (R6/R11/R13-proven incl. replays)
#define CLAIM_I(x)   ((x)*8)
#define GAL_I(x,q)   (64 + ((x)*4+(q))*8)
#define XROOT_I(x)   (320 + (x)*8)
#define ZERO_BYTES   (640*4)
// data region (never memset; single-XCD sc0 access; cross-step reads guarded at t==0)
#define FBASE 1024
#define HBU(x,t1,bb)  (FBASE + (x)*2048 + (t1)*1024 + (bb)*256)            // 256 uints: h f16x2
#define EGU(x,bb,k)   (FBASE + 16384 + (x)*2048 + (bb)*512 + (k)*64)      // 64 uints: E[32]|G[32] f16x2
#define SUMPF(x,bb,k) (FBASE + 32768 + (x)*128 + (bb)*32 + (k)*4)         // 4 floats: Se,Sg,Sw,gate
#define HPF(x,bb,r)   (FBASE + 33792 + (((x)*4+(bb))*32 + (r))*264)       // 264 floats: head partials

struct KP {
  const float *x, *Wih, *Whh, *bih, *bhh;
  const float *rkW, *rkb, *rsW, *rsb, *rgW, *rgb, *rgammaW, *rgammab;
  const float *wkW, *wkb, *wsW, *wsb, *weW, *web, *waW, *wab;
  const float *outW, *outb;
  float *out;
  float *memout;
  float *ws;
};

typedef _Float16 half2v __attribute__((ext_vector_type(2)));
union HU { unsigned u; half2v h; };

__device__ inline float sigf(float x){ return 1.f/(1.f+expf(-x)); }
__device__ inline float softplusf(float x){ return fmaxf(x,0.f) + log1pf(expf(-fabsf(x))); }
__device__ inline unsigned packh(float a, float b){
  HU z; z.h = half2v{(_Float16)a, (_Float16)b}; return z.u;
}
__device__ inline float h2lo(unsigned u){ HU z; z.u = u; return (float)z.h.x; }
__device__ inline float h2hi(unsigned u){ HU z; z.u = u; return (float)z.h.y; }
__device__ inline float dot2(unsigned w, unsigned a, float acc){
  HU wu, au; wu.u = w; au.u = a;
  return __builtin_amdgcn_fdot2(wu.h, au.h, acc, false);
}

// ---- sc0 (XCD-L2-local) DATA access (proven: single-XCD, sc1-barrier-ordered) ----
__device__ inline void stg_f(float* p, float v){
  asm volatile("global_store_dword %0, %1, off sc0" :: "v"(p), "v"(v) : "memory");
}
__device__ inline void stg_u(unsigned* p, unsigned v){
  asm volatile("global_store_dword %0, %1, off sc0" :: "v"(p), "v"(v) : "memory");
}
#define LDG4U(dst, addr) asm volatile("global_load_dwordx4 %0, %1, off sc0" : "=v"(dst) : "v"(addr) : "memory")
#define LDG4F(dst, addr) asm volatile("global_load_dwordx4 %0, %1, off sc0" : "=v"(dst) : "v"(addr) : "memory")
#define LDGU(dst, addr)  asm volatile("global_load_dword %0, %1, off sc0"  : "=v"(dst) : "v"(addr) : "memory")
#define LDGF(dst, addr)  asm volatile("global_load_dword %0, %1, off sc0"  : "=v"(dst) : "v"(addr) : "memory")
#define WAITV do { asm volatile("s_waitcnt vmcnt(0)" ::: "memory"); __builtin_amdgcn_sched_barrier(0); } while(0)

// ---- sc1 (agent/MALL) SYNC ops on memset lines (proven incl. replays) ----
#define AADD(p,v) __hip_atomic_fetch_add((p),(v),__ATOMIC_RELAXED,__HIP_MEMORY_SCOPE_AGENT)
#define ALD(p)    __hip_atomic_load((p),__ATOMIC_RELAXED,__HIP_MEMORY_SCOPE_AGENT)

#define SPIN(cond_expr) do { unsigned sp = 0; \
  while (cond_expr){ __builtin_amdgcn_s_sleep(2); \
    if (((++sp)&1023u)==0u && (__builtin_amdgcn_s_memrealtime()-t0) > 300000000ULL) break; } } while(0)

__device__ inline float headact(int o, float s){
  if (o < 64)  return tanhf(s);
  if (o == 64) return softplusf(s);
  if (o == 65) return sigf(s);
  if (o == 66) return 1.f + softplusf(s);
  if (o < 131) return tanhf(s);
  if (o == 131) return softplusf(s);
  if (o < 196) return sigf(s);
  return tanhf(s);
}
__device__ inline void head_src(const KP& P, int o, const float** row, float* bias){
  if (o < 64)       { *row = P.rkW + o*Cv;        *bias = P.rkb[o]; }
  else if (o == 64) { *row = P.rsW;               *bias = P.rsb[0]; }
  else if (o == 65) { *row = P.rgW;               *bias = P.rgb[0]; }
  else if (o == 66) { *row = P.rgammaW;           *bias = P.rgammab[0]; }
  else if (o < 131) { *row = P.wkW + (o-67)*Cv;   *bias = P.wkb[o-67]; }
  else if (o == 131){ *row = P.wsW;               *bias = P.wsb[0]; }
  else if (o < 196) { *row = P.weW + (o-132)*Cv;  *bias = P.web[o-132]; }
  else              { *row = P.waW + (o-196)*Cv;  *bias = P.wab[o-196]; }
}

__global__ __launch_bounds__(NTHR) void ntm_kernel(KP P){
  __shared__ unsigned Wg[64][420];
  __shared__ unsigned actL[4][420];   // [x(128)|rv(32)|h(256)] f16 pairs per local batch
  __shared__ float memL[128][66];
  __shared__ float gbp[64][4][2];     // split-K GEMM halves
  __shared__ float biasL[64];
  __shared__ float htmpf[16][5];
  __shared__ float headsL[264];
  __shared__ float knr[64], knw[64];
  __shared__ float scal[8];
  __shared__ float erL2[128], egL2[128], ewL[128];
  __shared__ float red[32][9];
  __shared__ float red2[2][4];
  __shared__ float sumS1[4][8][4];
  __shared__ float cEL[4], cGL[4];
  __shared__ float sumS4[8][4];
  __shared__ float rvpE[8][64], rvpG[8][64];
  __shared__ float rvfinE[64], rvfinG[64];
  __shared__ int sXcd, sRank;

  const int tid = threadIdx.x;
  float* wsf = P.ws;
  unsigned* wsu = (unsigned*)P.ws;
  int* wsi = (int*)P.ws;
  const unsigned long long t0 = __builtin_amdgcn_s_memrealtime();

  // ---- XCD discovery + rank claim (sc1 on memset line) ----
  if (tid == 0){
    unsigned xcc;
    asm volatile("s_getreg_b32 %0, hwreg(20, 0, 32)" : "=s"(xcc));  // HW_REG_XCC_ID
    int xc = (int)(xcc & 7u);
    int rk = AADD(&wsi[CLAIM_I(xc)], 1);
    sXcd = xc; sRank = rk & 31;
  }
  __syncthreads();
  const int xcd = sXcd, rank = sRank;
  const int bl_own = rank >> 3;
  const int rk8 = rank & 7;
  const int bglob = xcd*4 + bl_own;

  // ---- startup: gate W (f16) + bias into LDS; per-thread head-weight slice (tid<256) ----
  for (int idx = tid; idx < 64*416; idx += NTHR){
    int rl = idx / 416, u = idx % 416;
    int gr = (rl>>4)*Cv + rank*16 + (rl&15);
    int c0 = 2*u;
    float a, b2;
    if (c0 < 320){ a = P.Wih[gr*320 + c0]; b2 = P.Wih[gr*320 + c0 + 1]; }
    else { int q = c0 - 320; a = P.Whh[gr*512 + q]; b2 = P.Whh[gr*512 + q + 1]; }
    Wg[rl][u] = packh(a, b2);
  }
  if (tid < 64){
    int gr = (tid>>4)*Cv + rank*16 + (tid&15);
    biasL[tid] = P.bih[gr] + P.bhh[gr];
  }
  float wA[16], wB[16], bA = 0.f, bB = 0.f;
  if (tid < 256){
    const float* rowA; head_src(P, tid, &rowA, &bA);
    #pragma unroll
    for (int j = 0; j < 16; ++j) wA[j] = rowA[rank*16 + j];
    const float* rowB; head_src(P, 256 + (tid & 3), &rowB, &bB);
    #pragma unroll
    for (int j = 0; j < 16; ++j) wB[j] = rowB[rank*16 + j];
  }
  for (int idx = tid; idx < 128*66; idx += NTHR) ((float*)memL)[idx] = 0.f;
  __syncthreads();

  float cS = 0.f;                      // LSTM cell state (tid<64: (j,bb))
  int gs = 0;

  for (int t = 0; t < Sv; ++t){
    // ===== S1: stage x; combine rv from E/G; stage h(t-1); GEMM; c/h; h store; head partials; XB-A; outproj(t-1) =====
    {
      int bb = tid>>7, part = tid&127;
      const float* xp = P.x + ((size_t)(xcd*4+bb)*Sv + (size_t)t)*Iv + part*2;
      float2 xv = *(const float2*)xp;
      actL[bb][part] = packh(xv.x, xv.y);
      if (t > 0){
        uint4 hq = {};
        unsigned e0=0,e1=0,e2=0,e3=0,e4=0,e5=0,e6=0,e7=0,g0=0,g1=0,g2=0,g3=0,g4=0,g5=0,g6=0,g7=0;
        float4 sv = {0,0,0,0};
        int hb2 = tid>>6, hpart = tid&63;
        int b2 = tid>>5, j = tid&31;
        if (tid < 256){ LDG4U(hq, wsu + HBU(xcd,(t+1)&1,hb2) + hpart*4); }
        if (tid < 128){
          const unsigned* eb = wsu + EGU(xcd,b2,0) + j;
          LDGU(e0,eb+0*64); LDGU(e1,eb+1*64); LDGU(e2,eb+2*64); LDGU(e3,eb+3*64);
          LDGU(e4,eb+4*64); LDGU(e5,eb+5*64); LDGU(e6,eb+6*64); LDGU(e7,eb+7*64);
          const unsigned* ggb = eb + 32;
          LDGU(g0,ggb+0*64); LDGU(g1,ggb+1*64); LDGU(g2,ggb+2*64); LDGU(g3,ggb+3*64);
          LDGU(g4,ggb+4*64); LDGU(g5,ggb+5*64); LDGU(g6,ggb+6*64); LDGU(g7,ggb+7*64);
        }
        if (tid < 32){ LDG4F(sv, wsf + SUMPF(xcd, tid>>3, tid&7)); }
        WAITV;
        if (tid < 256){ *(uint4*)&actL[hb2][160 + hpart*4] = hq; }
        if (tid < 32) *(float4*)&sumS1[tid>>3][tid&7][0] = sv;
        __syncthreads();
        if (tid < 4){
          float Se = 0.f, Sg = 0.f;
          #pragma unroll
          for (int k2 = 0; k2 < 8; ++k2){ Se += sumS1[tid][k2][0]; Sg += sumS1[tid][k2][1]; }
          float g = sumS1[tid][0][3];
          cEL[tid] = (1.f - g)/Se;
          cGL[tid] = g/Sg;
        }
        __syncthreads();
        if (tid < 128){
          float Elo = h2lo(e0)+h2lo(e1)+h2lo(e2)+h2lo(e3)+h2lo(e4)+h2lo(e5)+h2lo(e6)+h2lo(e7);
          float Ehi = h2hi(e0)+h2hi(e1)+h2hi(e2)+h2hi(e3)+h2hi(e4)+h2hi(e5)+h2hi(e6)+h2hi(e7);
          float Glo = h2lo(g0)+h2lo(g1)+h2lo(g2)+h2lo(g3)+h2lo(g4)+h2lo(g5)+h2lo(g6)+h2lo(g7);
          float Ghi = h2hi(g0)+h2hi(g1)+h2hi(g2)+h2hi(g3)+h2hi(g4)+h2hi(g5)+h2hi(g6)+h2hi(g7);
          actL[b2][128 + j] = packh(cGL[b2]*Glo + cEL[b2]*Elo, cGL[b2]*Ghi + cEL[b2]*Ehi);
        }
      } else {
        for (int idx = tid; idx < 4*288; idx += NTHR){
          int bb2 = idx/288, u = 128 + idx%288;
          actL[bb2][u] = 0u;
        }
      }
    }
    __syncthreads();
    {  // gate GEMM, split-K 2-way: half=tid>>8 does u in [half*208, half*208+208)
      int half = tid>>8, l = tid&255;
      int g = l>>6, ll = l&63, rr = ll>>2, bb = ll&3, row = g*16+rr;
      const unsigned* wr = &Wg[row][0];
      const unsigned* ar = &actL[bb][0];
      int u0 = half*208;
      float a0 = (half==0) ? biasL[row] : 0.f, a1 = 0.f, a2 = 0.f, a3 = 0.f;
      #pragma unroll 13
      for (int u = u0; u < u0+208; u += 8){
        uint4 w0 = *(const uint4*)(wr+u);
        uint4 v0 = *(const uint4*)(ar+u);
        uint4 w1 = *(const uint4*)(wr+u+4);
        uint4 v1 = *(const uint4*)(ar+u+4);
        a0 = dot2(w0.x, v0.x, a0); a1 = dot2(w0.y, v0.y, a1);
        a2 = dot2(w0.z, v0.z, a2); a3 = dot2(w0.w, v0.w, a3);
        a0 = dot2(w1.x, v1.x, a0); a1 = dot2(w1.y, v1.y, a1);
        a2 = dot2(w1.z, v1.z, a2); a3 = dot2(w1.w, v1.w, a3);
      }
      gbp[row][bb][half] = (a0+a1)+(a2+a3);
    }
    __syncthreads();
    if (tid < 64){
      int j = tid>>2, bb = tid&3;
      float ig = gbp[j][bb][0]    + gbp[j][bb][1];
      float fg = gbp[16+j][bb][0] + gbp[16+j][bb][1];
      float gg = gbp[32+j][bb][0] + gbp[32+j][bb][1];
      float og = gbp[48+j][bb][0] + gbp[48+j][bb][1];
      cS = sigf(fg)*cS + sigf(ig)*tanhf(gg);
      htmpf[j][bb] = sigf(og)*tanhf(cS);
    }
    __syncthreads();
    if (tid < 32){
      int pr = tid>>2, bb = tid&3;
      stg_u(wsu + HBU(xcd,t&1,bb) + rank*8 + pr, packh(htmpf[2*pr][bb], htmpf[2*pr+1][bb]));
    }
    if (tid < 256){  // head partials over own 16 channels, all 260 outputs x 4 batches
      float p0=0.f,p1=0.f,p2=0.f,p3=0.f,q0=0.f,q1=0.f,q2=0.f,q3=0.f;
      #pragma unroll
      for (int j = 0; j < 16; ++j){
        float h0=htmpf[j][0], h1=htmpf[j][1], h2=htmpf[j][2], h3=htmpf[j][3];
        p0+=wA[j]*h0; p1+=wA[j]*h1; p2+=wA[j]*h2; p3+=wA[j]*h3;
        q0+=wB[j]*h0; q1+=wB[j]*h1; q2+=wB[j]*h2; q3+=wB[j]*h3;
      }
      stg_f(wsf + HPF(xcd,0,rank) + tid, p0);
      stg_f(wsf + HPF(xcd,1,rank) + tid, p1);
      stg_f(wsf + HPF(xcd,2,rank) + tid, p2);
      stg_f(wsf + HPF(xcd,3,rank) + tid, p3);
      if (tid < 4){
        int o2 = 256 + tid;
        stg_f(wsf + HPF(xcd,0,rank) + o2, q0);
        stg_f(wsf + HPF(xcd,1,rank) + o2, q1);
        stg_f(wsf + HPF(xcd,2,rank) + o2, q2);
        stg_f(wsf + HPF(xcd,3,rank) + o2, q3);
      }
    }
    // XB-A arrive (32-wide tree, sc1)
    WAITV;
    __syncthreads();
    if (tid == 0){
      int a = AADD(&wsi[GAL_I(xcd, rank>>3)], 1);
      if (a == 8*(gs+1) - 1) AADD(&wsi[XROOT_I(xcd)], 1);
    }
    if (t > 0){  // out-proj(t-1), hidden under XB-A
      if (tid < 256){
        int oo = tid>>3, kc = tid&7;
        int o = rk8*32 + oo;
        const float* wrow = P.outW + o*576 + kc*72;
        const unsigned* ab = &actL[bl_own][0];
        float p = 0.f;
        if (kc < 7){
          int u0 = 160 + kc*36;
          #pragma unroll 9
          for (int i = 0; i < 36; ++i){
            unsigned u = ab[u0+i];
            p += h2lo(u)*wrow[2*i] + h2hi(u)*wrow[2*i+1];
          }
        } else {
          #pragma unroll
          for (int i = 0; i < 4; ++i){
            unsigned u = ab[412+i];
            p += h2lo(u)*wrow[2*i] + h2hi(u)*wrow[2*i+1];
          }
          #pragma unroll 8
          for (int i = 0; i < 32; ++i){
            unsigned u = ab[128+i];
            p += h2lo(u)*wrow[8+2*i] + h2hi(u)*wrow[9+2*i];
          }
        }
        red[oo][kc] = p;
      }
      __syncthreads();
      if (tid < 32){
        int o2 = rk8*32 + tid;
        float s = P.outb[o2];
        #pragma unroll
        for (int k2 = 0; k2 < 8; ++k2) s += red[tid][k2];
        P.out[((size_t)bglob*Sv + (t-1))*Ov + o2] = s;
      }
    }
    if (tid == 0){ SPIN(ALD(&wsi[XROOT_I(xcd)]) < 4*(gs+1)); }
    __syncthreads();
    ++gs;

    // ===== S2': redundant head reduce (own batch); content addressing; sums+E/G; XB-B =====
    if (tid < 256){
      float s = bA, s2 = bB;
      #pragma unroll
      for (int rr = 0; rr < 4; ++rr){
        const float* hb = wsf + HPF(xcd, bl_own, rr*8);
        float a0,a1,a2,a3,a4,a5,a6,a7,b0,b1,b2,b3,b4,b5,b6,b7;
        int o2 = 256 + (tid & 3);
        LDGF(a0, hb + 0*264 + tid); LDGF(a1, hb + 1*264 + tid);
        LDGF(a2, hb + 2*264 + tid); LDGF(a3, hb + 3*264 + tid);
        LDGF(a4, hb + 4*264 + tid); LDGF(a5, hb + 5*264 + tid);
        LDGF(a6, hb + 6*264 + tid); LDGF(a7, hb + 7*264 + tid);
        LDGF(b0, hb + 0*264 + o2);  LDGF(b1, hb + 1*264 + o2);
        LDGF(b2, hb + 2*264 + o2);  LDGF(b3, hb + 3*264 + o2);
        LDGF(b4, hb + 4*264 + o2);  LDGF(b5, hb + 5*264 + o2);
        LDGF(b6, hb + 6*264 + o2);  LDGF(b7, hb + 7*264 + o2);
        WAITV;
        s  += ((a0+a1)+(a2+a3))+((a4+a5)+(a6+a7));
        s2 += ((b0+b1)+(b2+b3))+((b4+b5)+(b6+b7));
      }
      headsL[tid] = headact(tid, s);
      if (tid < 4) headsL[256+tid] = headact(256+tid, s2);
    }
    __syncthreads();
    if (tid < 64){
      float kr = headsL[tid], kw = headsL[67+tid];
      float sr = kr*kr, sw2 = kw*kw;
      #pragma unroll
      for (int off = 32; off; off >>= 1){ sr += __shfl_xor(sr, off); sw2 += __shfl_xor(sw2, off); }
      knr[tid] = kr * (1.f/fmaxf(sqrtf(sr), 1e-12f));
      knw[tid] = kw * (1.f/fmaxf(sqrtf(sw2), 1e-12f));
    }
    __syncthreads();
    {
      float str_r = headsL[64], gamma = headsL[66], str_w = headsL[131];
      float er = 0.f, eg = 0.f, ew = 0.f;
      if (tid < 128){
        float dr = 0.f, dw = 0.f, nn = 0.f;
        #pragma unroll 8
        for (int v = 0; v < 64; ++v){
          float m = memL[tid][v];
          dr += m*knr[v]; dw += m*knw[v]; nn += m*m;
        }
        float innm = 1.f/fmaxf(sqrtf(nn), 1e-12f);
        float tr = str_r*(dr*innm - 1.f);
        er = expf(tr);
        eg = expf(gamma*tr);
        ew = expf(str_w*(dw*innm - 1.f));
        erL2[tid] = er; egL2[tid] = eg; ewL[tid] = ew;
      }
      float s0 = er, s1 = eg, s2 = ew;
      #pragma unroll
      for (int off = 32; off; off >>= 1){
        s0 += __shfl_xor(s0, off); s1 += __shfl_xor(s1, off); s2 += __shfl_xor(s2, off);
      }
      if ((tid & 63) == 0 && tid < 128){
        int wv = tid>>6; red2[wv][0] = s0; red2[wv][1] = s1; red2[wv][2] = s2;
      }
      __syncthreads();
      if (tid == 0){
        float* sp = wsf + SUMPF(xcd,bl_own,rk8);
        stg_f(sp+0, red2[0][0]+red2[1][0]);
        stg_f(sp+1, red2[0][1]+red2[1][1]);
        stg_f(sp+2, red2[0][2]+red2[1][2]);
        stg_f(sp+3, headsL[65]);
      }
    }
    // unnormalized E/G partials on PRE-update memory (512 threads: 8 chunks x 16 rows)
    {
      int v = tid & 63, cc = tid >> 6;
      float pE = 0.f, pG = 0.f;
      #pragma unroll 8
      for (int j = 0; j < 16; ++j){
        int r = cc*16 + j;
        float m = memL[r][v];
        pE += erL2[r]*m; pG += egL2[r]*m;
      }
      rvpE[cc][v] = pE; rvpG[cc][v] = pG;
    }
    __syncthreads();
    if (tid < 64){
      float e = 0.f, g = 0.f;
      #pragma unroll
      for (int c2 = 0; c2 < 8; ++c2){ e += rvpE[c2][tid]; g += rvpG[c2][tid]; }
      rvfinE[tid] = e; rvfinG[tid] = g;
    }
    __syncthreads();
    if (tid < 32)
      stg_u(wsu + EGU(xcd,bl_own,rk8) + tid, packh(rvfinE[2*tid], rvfinE[2*tid+1]));
    else if (tid < 64)
      stg_u(wsu + EGU(xcd,bl_own,rk8) + tid, packh(rvfinG[2*(tid-32)], rvfinG[2*(tid-32)+1]));
    // XB-B (32-wide tree, sc1)
    WAITV;
    __syncthreads();
    if (tid == 0){
      int a = AADD(&wsi[GAL_I(xcd, rank>>3)], 1);
      if (a == 8*(gs+1) - 1) AADD(&wsi[XROOT_I(xcd)], 1);
      SPIN(ALD(&wsi[XROOT_I(xcd)]) < 4*(gs+1));
    }
    __syncthreads();
    ++gs;

    // ===== S4: memory update (local; needs global Sw) =====
    {
      float4 sv = {0,0,0,0};
      if (tid < 8){ LDG4F(sv, wsf + SUMPF(xcd,bl_own,tid)); }
      WAITV;
      if (tid < 8){ *(float4*)&sumS4[tid][0] = sv; }
    }
    __syncthreads();
    if (tid == 0){
      float Sw = 0.f;
      #pragma unroll
      for (int k2 = 0; k2 < 8; ++k2) Sw += sumS4[k2][2];
      scal[6] = Sw;
    }
    __syncthreads();
    {
      float rSw = 1.f/scal[6];
      #pragma unroll 4
      for (int e2 = 0; e2 < 16; ++e2){
        int flat = tid + e2*512;
        int r = flat >> 6, v2 = flat & 63;
        float ww = ewL[r]*rSw;
        memL[r][v2] = memL[r][v2]*(1.f - ww*headsL[132+v2]) + ww*headsL[196+v2];
      }
    }
    __syncthreads();
  }

  // ===== epilogue: stage h(S-1) + combined rv(S-1); out-proj(S-1) =====
  {
    uint4 hq = {};
    unsigned e0=0,e1=0,e2=0,e3=0,e4=0,e5=0,e6=0,e7=0,g0=0,g1=0,g2=0,g3=0,g4=0,g5=0,g6=0,g7=0;
    float4 sv = {0,0,0,0};
    int hb2 = tid>>6, hpart = tid&63;
    int b2 = tid>>5, j = tid&31;
    if (tid < 256){ LDG4U(hq, wsu + HBU(xcd,(Sv-1)&1,hb2) + hpart*4); }
    if (tid < 128){
      const unsigned* eb = wsu + EGU(xcd,b2,0) + j;
      LDGU(e0,eb+0*64); LDGU(e1,eb+1*64); LDGU(e2,eb+2*64); LDGU(e3,eb+3*64);
      LDGU(e4,eb+4*64); LDGU(e5,eb+5*64); LDGU(e6,eb+6*64); LDGU(e7,eb+7*64);
      const unsigned* ggb = eb + 32;
      LDGU(g0,ggb+0*64); LDGU(g1,ggb+1*64); LDGU(g2,ggb+2*64); LDGU(g3,ggb+3*64);
      LDGU(g4,ggb+4*64); LDGU(g5,ggb+5*64); LDGU(g6,ggb+6*64); LDGU(g7,ggb+7*64);
    }
    if (tid < 32){ LDG4F(sv, wsf + SUMPF(xcd, tid>>3, tid&7)); }
    WAITV;
    if (tid < 256){ *(uint4*)&actL[hb2][160 + hpart*4] = hq; }
    if (tid < 32) *(float4*)&sumS1[tid>>3][tid&7][0] = sv;
    __syncthreads();
    if (tid < 4){
      float Se = 0.f, Sg = 0.f;
      #pragma unroll
      for (int k2 = 0; k2 < 8; ++k2){ Se += sumS1[tid][k2][0]; Sg += sumS1[tid][k2][1]; }
      float g = sumS1[tid][0][3];
      cEL[tid] = (1.f - g)/Se;
      cGL[tid] = g/Sg;
    }
    __syncthreads();
    if (tid < 128){
      float Elo = h2lo(e0)+h2lo(e1)+h2lo(e2)+h2lo(e3)+h2lo(e4)+h2lo(e5)+h2lo(e6)+h2lo(e7);
      float Ehi = h2hi(e0)+h2hi(e1)+h2hi(e2)+h2hi(e3)+h2hi(e4)+h2hi(e5)+h2hi(e6)+h2hi(e7);
      float Glo = h2lo(g0)+h2lo(g1)+h2lo(g2)+h2lo(g3)+h2lo(g4)+h2lo(g5)+h2lo(g6)+h2lo(g7);
      float Ghi = h2hi(g0)+h2hi(g1)+h2hi(g2)+h2hi(g3)+h2hi(g4)+h2hi(g5)+h2hi(g6)+h2hi(g7);
      actL[b2][128 + j] = packh(cGL[b2]*Glo + cEL[b2]*Elo, cGL[b2]*Ghi + cEL[b2]*Ehi);
    }
  }
  __syncthreads();
  {
    if (tid < 256){
      int oo = tid>>3, kc = tid&7;
      int o = rk8*32 + oo;
      const float* wrow = P.outW + o*576 + kc*72;
      const unsigned* ab = &actL[bl_own][0];
      float p = 0.f;
      if (kc < 7){
        int u0 = 160 + kc*36;
        #pragma unroll 9
        for (int i = 0; i < 36; ++i){
          unsigned u = ab[u0+i];
          p += h2lo(u)*wrow[2*i] + h2hi(u)*wrow[2*i+1];
        }
      } else {
        #pragma unroll
        for (int i = 0; i < 4; ++i){
          unsigned u = ab[412+i];
          p += h2lo(u)*wrow[2*i] + h2hi(u)*wrow[2*i+1];
        }
        #pragma unroll 8
        for (int i = 0; i < 32; ++i){
          unsigned u = ab[128+i];
          p += h2lo(u)*wrow[8+2*i] + h2hi(u)*wrow[9+2*i];
        }
      }
      red[oo][kc] = p;
    }
    __syncthreads();
    if (tid < 32){
      int o2 = rk8*32 + tid;
      float s = P.outb[o2];
      #pragma unroll
      for (int k2 = 0; k2 < 8; ++k2) s += red[tid][k2];
      P.out[((size_t)bglob*Sv + (Sv-1))*Ov + o2] = s;
    }
  }
  // ===== epilogue: final memory writeout =====
  for (int e2 = 0; e2 < 16; ++e2){
    int flat = tid + e2*512;
    int r = flat >> 6, v2 = flat & 63;
    P.memout[((size_t)bglob*Nv + (size_t)rk8*128 + r)*Vv + v2] = memL[r][v2];
  }
}

extern "C" void kernel_launch(void* const* d_in, const int* in_sizes, int n_in,
                              void* d_out, int out_size, void* d_ws, size_t ws_size,
                              hipStream_t stream) {
  (void)in_sizes; (void)n_in; (void)out_size; (void)ws_size;
  KP p;
  p.x       = (const float*)d_in[0];
  p.Wih     = (const float*)d_in[1];
  p.Whh     = (const float*)d_in[2];
  p.bih     = (const float*)d_in[3];
  p.bhh     = (const float*)d_in[4];
  p.rkW     = (const float*)d_in[5];  p.rkb     = (const float*)d_in[6];
  p.rsW     = (const float*)d_in[7];  p.rsb     = (const float*)d_in[8];
  p.rgW     = (const float*)d_in[9];  p.rgb     = (const float*)d_in[10];
  p.rgammaW = (const float*)d_in[13]; p.rgammab = (const float*)d_in[14];
  p.wkW     = (const float*)d_in[15]; p.wkb     = (const float*)d_in[16];
  p.wsW     = (const float*)d_in[17]; p.wsb     = (const float*)d_in[18];
  p.weW     = (const float*)d_in[19]; p.web     = (const float*)d_in[20];
  p.waW     = (const float*)d_in[21]; p.wab     = (const float*)d_in[22];
  p.outW    = (const float*)d_in[23]; p.outb    = (const float*)d_in[24];
  p.out     = (float*)d_out;
  p.memout  = (float*)d_out + (size_t)Bv*Sv*Ov;
  p.ws      = (float*)d_ws;

  hipMemsetAsync(d_ws, 0, ZERO_BYTES, stream);   // sync lines only (claim + GAL + XROOT)
  hipLaunchKernelGGL(ntm_kernel, dim3(NBLK), dim3(NTHR), 0, stream, p);
}

// Round 15
// 4244.513 us; speedup vs baseline: 1.3847x; 1.3847x over previous
//
#include <hip/hip_runtime.h>

#define Bv 32
#define Sv 256
#define Iv 256
#define Cv 512
#define Nv 1024
#define Vv 64
#define Ov 256
#define NBLK 256
#define NTHR 256

// ---- ws layout (int indices) ----
// sync region: host-memset each launch; sc1(agent)-only atomics/spins (R6/R11/R13-proven incl. replays)
#define CLAIM_I(x)   ((x)*8)
#define GAL_I(x,q)   (64 + ((x)*4+(q))*8)
#define XROOT_I(x)   (320 + (x)*8)
#define ZERO_BYTES   (640*4)
// data region (never memset; single-XCD sc0 access; cross-step reads guarded at t==0)
#define FBASE 1024
#define HBU(x,t1,bb)  (FBASE + (x)*2048 + (t1)*1024 + (bb)*256)            // 256 uints: h f16x2
#define EGU(x,bb,k)   (FBASE + 16384 + (x)*2048 + (bb)*512 + (k)*64)      // 64 uints: E[32]|G[32] f16x2
#define SUMPF(x,bb,k) (FBASE + 32768 + (x)*128 + (bb)*32 + (k)*4)         // 4 floats: Se,Sg,Sw,gate
#define HPF(x,bb,r)   (FBASE + 33792 + (((x)*4+(bb))*32 + (r))*264)       // 264 floats: head partials

struct KP {
  const float *x, *Wih, *Whh, *bih, *bhh;
  const float *rkW, *rkb, *rsW, *rsb, *rgW, *rgb, *rgammaW, *rgammab;
  const float *wkW, *wkb, *wsW, *wsb, *weW, *web, *waW, *wab;
  const float *outW, *outb;
  float *out;
  float *memout;
  float *ws;
};

typedef _Float16 half2v __attribute__((ext_vector_type(2)));
union HU { unsigned u; half2v h; };

__device__ inline float sigf(float x){ return 1.f/(1.f+expf(-x)); }
__device__ inline float softplusf(float x){ return fmaxf(x,0.f) + log1pf(expf(-fabsf(x))); }
__device__ inline unsigned packh(float a, float b){
  HU z; z.h = half2v{(_Float16)a, (_Float16)b}; return z.u;
}
__device__ inline float h2lo(unsigned u){ HU z; z.u = u; return (float)z.h.x; }
__device__ inline float h2hi(unsigned u){ HU z; z.u = u; return (float)z.h.y; }
__device__ inline float dot2(unsigned w, unsigned a, float acc){
  HU wu, au; wu.u = w; au.u = a;
  return __builtin_amdgcn_fdot2(wu.h, au.h, acc, false);
}

// ---- sc0 (XCD-L2-local) DATA access (proven: single-XCD, sc1-barrier-ordered) ----
__device__ inline void stg_f(float* p, float v){
  asm volatile("global_store_dword %0, %1, off sc0" :: "v"(p), "v"(v) : "memory");
}
__device__ inline void stg_u(unsigned* p, unsigned v){
  asm volatile("global_store_dword %0, %1, off sc0" :: "v"(p), "v"(v) : "memory");
}
#define LDG4U(dst, addr) asm volatile("global_load_dwordx4 %0, %1, off sc0" : "=v"(dst) : "v"(addr) : "memory")
#define LDG4F(dst, addr) asm volatile("global_load_dwordx4 %0, %1, off sc0" : "=v"(dst) : "v"(addr) : "memory")
#define LDGU(dst, addr)  asm volatile("global_load_dword %0, %1, off sc0"  : "=v"(dst) : "v"(addr) : "memory")
#define LDGF(dst, addr)  asm volatile("global_load_dword %0, %1, off sc0"  : "=v"(dst) : "v"(addr) : "memory")
#define WAITV do { asm volatile("s_waitcnt vmcnt(0)" ::: "memory"); __builtin_amdgcn_sched_barrier(0); } while(0)

// ---- sc1 (agent/MALL) SYNC ops on memset lines (proven incl. replays) ----
#define AADD(p,v) __hip_atomic_fetch_add((p),(v),__ATOMIC_RELAXED,__HIP_MEMORY_SCOPE_AGENT)
#define ALD(p)    __hip_atomic_load((p),__ATOMIC_RELAXED,__HIP_MEMORY_SCOPE_AGENT)

#define SPIN(cond_expr) do { unsigned sp = 0; \
  while (cond_expr){ __builtin_amdgcn_s_sleep(2); \
    if (((++sp)&1023u)==0u && (__builtin_amdgcn_s_memrealtime()-t0) > 300000000ULL) break; } } while(0)

__device__ inline float headact(int o, float s){
  if (o < 64)  return tanhf(s);
  if (o == 64) return softplusf(s);
  if (o == 65) return sigf(s);
  if (o == 66) return 1.f + softplusf(s);
  if (o < 131) return tanhf(s);
  if (o == 131) return softplusf(s);
  if (o < 196) return sigf(s);
  return tanhf(s);
}
__device__ inline void head_src(const KP& P, int o, const float** row, float* bias){
  if (o < 64)       { *row = P.rkW + o*Cv;        *bias = P.rkb[o]; }
  else if (o == 64) { *row = P.rsW;               *bias = P.rsb[0]; }
  else if (o == 65) { *row = P.rgW;               *bias = P.rgb[0]; }
  else if (o == 66) { *row = P.rgammaW;           *bias = P.rgammab[0]; }
  else if (o < 131) { *row = P.wkW + (o-67)*Cv;   *bias = P.wkb[o-67]; }
  else if (o == 131){ *row = P.wsW;               *bias = P.wsb[0]; }
  else if (o < 196) { *row = P.weW + (o-132)*Cv;  *bias = P.web[o-132]; }
  else              { *row = P.waW + (o-196)*Cv;  *bias = P.wab[o-196]; }
}

__global__ __launch_bounds__(NTHR) void ntm_kernel(KP P){
  __shared__ unsigned actL[4][420];   // [x(128)|rv(32)|h(256)] f16 pairs per local batch
  __shared__ float memL[128][66];
  __shared__ float gbq[4][4][68];     // GEMM quarter-partials [q][batch][row]
  __shared__ float biasL[64];
  __shared__ float htmpf[16][5];
  __shared__ float headsL[264];
  __shared__ float knr[64], knw[64];
  __shared__ float scal[8];
  __shared__ float erL2[128], egL2[128], ewL[128];
  __shared__ float red[32][9];
  __shared__ float red2[2][4];
  __shared__ float sumS1[4][8][4];
  __shared__ float cEL[4], cGL[4];
  __shared__ float sumS4[8][4];
  __shared__ float rvpE[4][64], rvpG[4][64];
  __shared__ float rvfinE[64], rvfinG[64];
  __shared__ int sXcd, sRank;

  const int tid = threadIdx.x;
  float* wsf = P.ws;
  unsigned* wsu = (unsigned*)P.ws;
  int* wsi = (int*)P.ws;
  const unsigned long long t0 = __builtin_amdgcn_s_memrealtime();

  // ---- XCD discovery + rank claim (sc1 on memset line) ----
  if (tid == 0){
    unsigned xcc;
    asm volatile("s_getreg_b32 %0, hwreg(20, 0, 32)" : "=s"(xcc));  // HW_REG_XCC_ID
    int xc = (int)(xcc & 7u);
    int rk = AADD(&wsi[CLAIM_I(xc)], 1);
    sXcd = xc; sRank = rk & 31;
  }
  __syncthreads();
  const int xcd = sXcd, rank = sRank;
  const int bl_own = rank >> 3;
  const int rk8 = rank & 7;
  const int bglob = xcd*4 + bl_own;

  // ---- startup: gate W (f16) into VGPRs (thread = (quarter q, row r)); bias; head slices ----
  const int qw = tid >> 6;            // column-quarter (= wave id)
  const int rw = tid & 63;            // gate-row within block
  const int grw = (rw>>4)*Cv + rank*16 + (rw&15);
  uint4 wreg[26];
  {
    #pragma unroll
    for (int jj = 0; jj < 26; ++jj){
      unsigned uu[4];
      #pragma unroll
      for (int c = 0; c < 4; ++c){
        int e = qw*208 + 8*jj + 2*c;
        float2 w2;
        if (e < 320) w2 = *(const float2*)(P.Wih + grw*320 + e);
        else         w2 = *(const float2*)(P.Whh + grw*512 + (e-320));
        uu[c] = packh(w2.x, w2.y);
      }
      wreg[jj].x = uu[0]; wreg[jj].y = uu[1]; wreg[jj].z = uu[2]; wreg[jj].w = uu[3];
    }
  }
  if (tid < 64){
    int gr = (tid>>4)*Cv + rank*16 + (tid&15);
    biasL[tid] = P.bih[gr] + P.bhh[gr];
  }
  float wA[16], wB[16], bA = 0.f, bB = 0.f;
  {
    const float* rowA; head_src(P, tid, &rowA, &bA);
    #pragma unroll
    for (int j = 0; j < 16; ++j) wA[j] = rowA[rank*16 + j];
    const float* rowB; head_src(P, 256 + (tid & 3), &rowB, &bB);
    #pragma unroll
    for (int j = 0; j < 16; ++j) wB[j] = rowB[rank*16 + j];
  }
  for (int idx = tid; idx < 128*66; idx += NTHR) ((float*)memL)[idx] = 0.f;
  __syncthreads();

  float cS = 0.f;                      // LSTM cell state (tid<64: (j,bb))
  int gs = 0;

  for (int t = 0; t < Sv; ++t){
    // ===== S1: stage x; combine rv from E/G; stage h(t-1); GEMM; c/h; h store; head partials; XB-A; outproj(t-1) =====
    {
      int bb = tid>>6, part = tid&63;
      const float* xp = P.x + ((size_t)(xcd*4+bb)*Sv + (size_t)t)*Iv + part*4;
      float4 xv = *(const float4*)xp;
      actL[bb][part*2]   = packh(xv.x, xv.y);
      actL[bb][part*2+1] = packh(xv.z, xv.w);
      if (t > 0){
        uint4 hq;
        unsigned e0,e1,e2,e3,e4,e5,e6,e7,g0,g1,g2,g3,g4,g5,g6,g7;
        float4 sv = {0,0,0,0};
        int b2 = tid>>5, j = tid&31;
        LDG4U(hq, wsu + HBU(xcd,(t+1)&1,bb) + part*4);
        if (tid < 128){
          const unsigned* eb = wsu + EGU(xcd,b2,0) + j;
          LDGU(e0,eb+0*64); LDGU(e1,eb+1*64); LDGU(e2,eb+2*64); LDGU(e3,eb+3*64);
          LDGU(e4,eb+4*64); LDGU(e5,eb+5*64); LDGU(e6,eb+6*64); LDGU(e7,eb+7*64);
          const unsigned* ggb = eb + 32;
          LDGU(g0,ggb+0*64); LDGU(g1,ggb+1*64); LDGU(g2,ggb+2*64); LDGU(g3,ggb+3*64);
          LDGU(g4,ggb+4*64); LDGU(g5,ggb+5*64); LDGU(g6,ggb+6*64); LDGU(g7,ggb+7*64);
        }
        if (tid < 32){ LDG4F(sv, wsf + SUMPF(xcd, tid>>3, tid&7)); }
        WAITV;
        *(uint4*)&actL[bb][160 + part*4] = hq;
        if (tid < 32) *(float4*)&sumS1[tid>>3][tid&7][0] = sv;
        __syncthreads();
        if (tid < 4){
          float Se = 0.f, Sg = 0.f;
          #pragma unroll
          for (int k2 = 0; k2 < 8; ++k2){ Se += sumS1[tid][k2][0]; Sg += sumS1[tid][k2][1]; }
          float g = sumS1[tid][0][3];
          cEL[tid] = (1.f - g)/Se;
          cGL[tid] = g/Sg;
        }
        __syncthreads();
        if (tid < 128){
          float Elo = h2lo(e0)+h2lo(e1)+h2lo(e2)+h2lo(e3)+h2lo(e4)+h2lo(e5)+h2lo(e6)+h2lo(e7);
          float Ehi = h2hi(e0)+h2hi(e1)+h2hi(e2)+h2hi(e3)+h2hi(e4)+h2hi(e5)+h2hi(e6)+h2hi(e7);
          float Glo = h2lo(g0)+h2lo(g1)+h2lo(g2)+h2lo(g3)+h2lo(g4)+h2lo(g5)+h2lo(g6)+h2lo(g7);
          float Ghi = h2hi(g0)+h2hi(g1)+h2hi(g2)+h2hi(g3)+h2hi(g4)+h2hi(g5)+h2hi(g6)+h2hi(g7);
          actL[b2][128 + j] = packh(cGL[b2]*Glo + cEL[b2]*Elo, cGL[b2]*Ghi + cEL[b2]*Ehi);
        }
      } else {
        for (int idx = tid; idx < 4*288; idx += NTHR){
          int bb2 = idx/288, u = 128 + idx%288;
          actL[bb2][u] = 0u;
        }
      }
    }
    __syncthreads();
    {  // gate GEMM: weights in VGPRs, activations broadcast from LDS (all lanes same addr)
      const int base0 = qw*104;
      float a00=0.f,a01=0.f,a10=0.f,a11=0.f,a20=0.f,a21=0.f,a30=0.f,a31=0.f;
      #pragma unroll
      for (int jj = 0; jj < 26; ++jj){
        uint4 w = wreg[jj];
        uint4 v0 = *(const uint4*)&actL[0][base0+4*jj];
        uint4 v1 = *(const uint4*)&actL[1][base0+4*jj];
        uint4 v2 = *(const uint4*)&actL[2][base0+4*jj];
        uint4 v3 = *(const uint4*)&actL[3][base0+4*jj];
        a00=dot2(w.x,v0.x,a00); a01=dot2(w.y,v0.y,a01); a00=dot2(w.z,v0.z,a00); a01=dot2(w.w,v0.w,a01);
        a10=dot2(w.x,v1.x,a10); a11=dot2(w.y,v1.y,a11); a10=dot2(w.z,v1.z,a10); a11=dot2(w.w,v1.w,a11);
        a20=dot2(w.x,v2.x,a20); a21=dot2(w.y,v2.y,a21); a20=dot2(w.z,v2.z,a20); a21=dot2(w.w,v2.w,a21);
        a30=dot2(w.x,v3.x,a30); a31=dot2(w.y,v3.y,a31); a30=dot2(w.z,v3.z,a30); a31=dot2(w.w,v3.w,a31);
      }
      gbq[qw][0][rw] = a00+a01;
      gbq[qw][1][rw] = a10+a11;
      gbq[qw][2][rw] = a20+a21;
      gbq[qw][3][rw] = a30+a31;
    }
    __syncthreads();
    if (tid < 64){
      int j = tid>>2, bb = tid&3;
      float ig = biasL[j]    + gbq[0][bb][j]    + gbq[1][bb][j]    + gbq[2][bb][j]    + gbq[3][bb][j];
      float fg = biasL[16+j] + gbq[0][bb][16+j] + gbq[1][bb][16+j] + gbq[2][bb][16+j] + gbq[3][bb][16+j];
      float gg = biasL[32+j] + gbq[0][bb][32+j] + gbq[1][bb][32+j] + gbq[2][bb][32+j] + gbq[3][bb][32+j];
      float og = biasL[48+j] + gbq[0][bb][48+j] + gbq[1][bb][48+j] + gbq[2][bb][48+j] + gbq[3][bb][48+j];
      cS = sigf(fg)*cS + sigf(ig)*tanhf(gg);
      htmpf[j][bb] = sigf(og)*tanhf(cS);
    }
    __syncthreads();
    if (tid < 32){
      int pr = tid>>2, bb = tid&3;
      stg_u(wsu + HBU(xcd,t&1,bb) + rank*8 + pr, packh(htmpf[2*pr][bb], htmpf[2*pr+1][bb]));
    }
    {  // head partials over own 16 channels, all 260 outputs x 4 batches
      float p0=0.f,p1=0.f,p2=0.f,p3=0.f,q0=0.f,q1=0.f,q2=0.f,q3=0.f;
      #pragma unroll
      for (int j = 0; j < 16; ++j){
        float h0=htmpf[j][0], h1=htmpf[j][1], h2=htmpf[j][2], h3=htmpf[j][3];
        p0+=wA[j]*h0; p1+=wA[j]*h1; p2+=wA[j]*h2; p3+=wA[j]*h3;
        q0+=wB[j]*h0; q1+=wB[j]*h1; q2+=wB[j]*h2; q3+=wB[j]*h3;
      }
      stg_f(wsf + HPF(xcd,0,rank) + tid, p0);
      stg_f(wsf + HPF(xcd,1,rank) + tid, p1);
      stg_f(wsf + HPF(xcd,2,rank) + tid, p2);
      stg_f(wsf + HPF(xcd,3,rank) + tid, p3);
      if (tid < 4){
        int o2 = 256 + tid;
        stg_f(wsf + HPF(xcd,0,rank) + o2, q0);
        stg_f(wsf + HPF(xcd,1,rank) + o2, q1);
        stg_f(wsf + HPF(xcd,2,rank) + o2, q2);
        stg_f(wsf + HPF(xcd,3,rank) + o2, q3);
      }
    }
    // XB-A arrive (32-wide tree, sc1)
    WAITV;
    __syncthreads();
    if (tid == 0){
      int a = AADD(&wsi[GAL_I(xcd, rank>>3)], 1);
      if (a == 8*(gs+1) - 1) AADD(&wsi[XROOT_I(xcd)], 1);
    }
    if (t > 0){  // out-proj(t-1), hidden under XB-A
      int oo = tid>>3, kc = tid&7;
      int o = rk8*32 + oo;
      const float* wrow = P.outW + o*576 + kc*72;
      const unsigned* ab = &actL[bl_own][0];
      float p = 0.f;
      if (kc < 7){
        int u0 = 160 + kc*36;
        #pragma unroll 9
        for (int i = 0; i < 36; ++i){
          unsigned u = ab[u0+i];
          p += h2lo(u)*wrow[2*i] + h2hi(u)*wrow[2*i+1];
        }
      } else {
        #pragma unroll
        for (int i = 0; i < 4; ++i){
          unsigned u = ab[412+i];
          p += h2lo(u)*wrow[2*i] + h2hi(u)*wrow[2*i+1];
        }
        #pragma unroll 8
        for (int i = 0; i < 32; ++i){
          unsigned u = ab[128+i];
          p += h2lo(u)*wrow[8+2*i] + h2hi(u)*wrow[9+2*i];
        }
      }
      red[oo][kc] = p;
      __syncthreads();
      if (tid < 32){
        int o2 = rk8*32 + tid;
        float s = P.outb[o2];
        #pragma unroll
        for (int k2 = 0; k2 < 8; ++k2) s += red[tid][k2];
        P.out[((size_t)bglob*Sv + (t-1))*Ov + o2] = s;
      }
    }
    if (tid == 0){ SPIN(ALD(&wsi[XROOT_I(xcd)]) < 4*(gs+1)); }
    __syncthreads();
    ++gs;

    // ===== S2': redundant head reduce (own batch); content addressing; sums+E/G; XB-B =====
    {
      float s = bA, s2 = bB;
      #pragma unroll
      for (int rr = 0; rr < 4; ++rr){
        const float* hb = wsf + HPF(xcd, bl_own, rr*8);
        float a0,a1,a2,a3,a4,a5,a6,a7,b0,b1,b2,b3,b4,b5,b6,b7;
        int o2 = 256 + (tid & 3);
        LDGF(a0, hb + 0*264 + tid); LDGF(a1, hb + 1*264 + tid);
        LDGF(a2, hb + 2*264 + tid); LDGF(a3, hb + 3*264 + tid);
        LDGF(a4, hb + 4*264 + tid); LDGF(a5, hb + 5*264 + tid);
        LDGF(a6, hb + 6*264 + tid); LDGF(a7, hb + 7*264 + tid);
        LDGF(b0, hb + 0*264 + o2);  LDGF(b1, hb + 1*264 + o2);
        LDGF(b2, hb + 2*264 + o2);  LDGF(b3, hb + 3*264 + o2);
        LDGF(b4, hb + 4*264 + o2);  LDGF(b5, hb + 5*264 + o2);
        LDGF(b6, hb + 6*264 + o2);  LDGF(b7, hb + 7*264 + o2);
        WAITV;
        s  += ((a0+a1)+(a2+a3))+((a4+a5)+(a6+a7));
        s2 += ((b0+b1)+(b2+b3))+((b4+b5)+(b6+b7));
      }
      headsL[tid] = headact(tid, s);
      if (tid < 4) headsL[256+tid] = headact(256+tid, s2);
    }
    __syncthreads();
    if (tid < 64){
      float kr = headsL[tid], kw = headsL[67+tid];
      float sr = kr*kr, sw2 = kw*kw;
      #pragma unroll
      for (int off = 32; off; off >>= 1){ sr += __shfl_xor(sr, off); sw2 += __shfl_xor(sw2, off); }
      knr[tid] = kr * (1.f/fmaxf(sqrtf(sr), 1e-12f));
      knw[tid] = kw * (1.f/fmaxf(sqrtf(sw2), 1e-12f));
    }
    __syncthreads();
    {
      float str_r = headsL[64], gamma = headsL[66], str_w = headsL[131];
      float er = 0.f, eg = 0.f, ew = 0.f;
      if (tid < 128){
        float dr = 0.f, dw = 0.f, nn = 0.f;
        #pragma unroll 8
        for (int v = 0; v < 64; ++v){
          float m = memL[tid][v];
          dr += m*knr[v]; dw += m*knw[v]; nn += m*m;
        }
        float innm = 1.f/fmaxf(sqrtf(nn), 1e-12f);
        float tr = str_r*(dr*innm - 1.f);
        er = expf(tr);
        eg = expf(gamma*tr);
        ew = expf(str_w*(dw*innm - 1.f));
        erL2[tid] = er; egL2[tid] = eg; ewL[tid] = ew;
      }
      float s0 = er, s1 = eg, s2 = ew;
      #pragma unroll
      for (int off = 32; off; off >>= 1){
        s0 += __shfl_xor(s0, off); s1 += __shfl_xor(s1, off); s2 += __shfl_xor(s2, off);
      }
      if ((tid & 63) == 0 && tid < 128){
        int wv = tid>>6; red2[wv][0] = s0; red2[wv][1] = s1; red2[wv][2] = s2;
      }
      __syncthreads();
      if (tid == 0){
        float* sp = wsf + SUMPF(xcd,bl_own,rk8);
        stg_f(sp+0, red2[0][0]+red2[1][0]);
        stg_f(sp+1, red2[0][1]+red2[1][1]);
        stg_f(sp+2, red2[0][2]+red2[1][2]);
        stg_f(sp+3, headsL[65]);
      }
    }
    // unnormalized E/G partials on PRE-update memory
    {
      int v = tid & 63, cc = tid >> 6;
      float pE = 0.f, pG = 0.f;
      #pragma unroll 8
      for (int j = 0; j < 32; ++j){
        int r = cc*32 + j;
        float m = memL[r][v];
        pE += erL2[r]*m; pG += egL2[r]*m;
      }
      rvpE[cc][v] = pE; rvpG[cc][v] = pG;
    }
    __syncthreads();
    if (tid < 64){
      rvfinE[tid] = rvpE[0][tid]+rvpE[1][tid]+rvpE[2][tid]+rvpE[3][tid];
      rvfinG[tid] = rvpG[0][tid]+rvpG[1][tid]+rvpG[2][tid]+rvpG[3][tid];
    }
    __syncthreads();
    if (tid < 32)
      stg_u(wsu + EGU(xcd,bl_own,rk8) + tid, packh(rvfinE[2*tid], rvfinE[2*tid+1]));
    else if (tid < 64)
      stg_u(wsu + EGU(xcd,bl_own,rk8) + tid, packh(rvfinG[2*(tid-32)], rvfinG[2*(tid-32)+1]));
    // XB-B (32-wide tree, sc1)
    WAITV;
    __syncthreads();
    if (tid == 0){
      int a = AADD(&wsi[GAL_I(xcd, rank>>3)], 1);
      if (a == 8*(gs+1) - 1) AADD(&wsi[XROOT_I(xcd)], 1);
      SPIN(ALD(&wsi[XROOT_I(xcd)]) < 4*(gs+1));
    }
    __syncthreads();
    ++gs;

    // ===== S4: memory update (local; needs global Sw) =====
    {
      float4 sv = {0,0,0,0};
      if (tid < 8){ LDG4F(sv, wsf + SUMPF(xcd,bl_own,tid)); }
      WAITV;
      if (tid < 8){ *(float4*)&sumS4[tid][0] = sv; }
    }
    __syncthreads();
    if (tid == 0){
      float Sw = 0.f;
      #pragma unroll
      for (int k2 = 0; k2 < 8; ++k2) Sw += sumS4[k2][2];
      scal[6] = Sw;
    }
    __syncthreads();
    {
      float rSw = 1.f/scal[6];
      #pragma unroll 4
      for (int e2 = 0; e2 < 32; ++e2){
        int flat = tid + e2*256;
        int r = flat >> 6, v2 = flat & 63;
        float ww = ewL[r]*rSw;
        memL[r][v2] = memL[r][v2]*(1.f - ww*headsL[132+v2]) + ww*headsL[196+v2];
      }
    }
    __syncthreads();
  }

  // ===== epilogue: stage h(S-1) + combined rv(S-1); out-proj(S-1) =====
  {
    int bb = tid>>6, part = tid&63;
    uint4 hq;
    unsigned e0,e1,e2,e3,e4,e5,e6,e7,g0,g1,g2,g3,g4,g5,g6,g7;
    float4 sv = {0,0,0,0};
    int b2 = tid>>5, j = tid&31;
    LDG4U(hq, wsu + HBU(xcd,(Sv-1)&1,bb) + part*4);
    if (tid < 128){
      const unsigned* eb = wsu + EGU(xcd,b2,0) + j;
      LDGU(e0,eb+0*64); LDGU(e1,eb+1*64); LDGU(e2,eb+2*64); LDGU(e3,eb+3*64);
      LDGU(e4,eb+4*64); LDGU(e5,eb+5*64); LDGU(e6,eb+6*64); LDGU(e7,eb+7*64);
      const unsigned* ggb = eb + 32;
      LDGU(g0,ggb+0*64); LDGU(g1,ggb+1*64); LDGU(g2,ggb+2*64); LDGU(g3,ggb+3*64);
      LDGU(g4,ggb+4*64); LDGU(g5,ggb+5*64); LDGU(g6,ggb+6*64); LDGU(g7,ggb+7*64);
    }
    if (tid < 32){ LDG4F(sv, wsf + SUMPF(xcd, tid>>3, tid&7)); }
    WAITV;
    *(uint4*)&actL[bb][160 + part*4] = hq;
    if (tid < 32) *(float4*)&sumS1[tid>>3][tid&7][0] = sv;
    __syncthreads();
    if (tid < 4){
      float Se = 0.f, Sg = 0.f;
      #pragma unroll
      for (int k2 = 0; k2 < 8; ++k2){ Se += sumS1[tid][k2][0]; Sg += sumS1[tid][k2][1]; }
      float g = sumS1[tid][0][3];
      cEL[tid] = (1.f - g)/Se;
      cGL[tid] = g/Sg;
    }
    __syncthreads();
    if (tid < 128){
      float Elo = h2lo(e0)+h2lo(e1)+h2lo(e2)+h2lo(e3)+h2lo(e4)+h2lo(e5)+h2lo(e6)+h2lo(e7);
      float Ehi = h2hi(e0)+h2hi(e1)+h2hi(e2)+h2hi(e3)+h2hi(e4)+h2hi(e5)+h2hi(e6)+h2hi(e7);
      float Glo = h2lo(g0)+h2lo(g1)+h2lo(g2)+h2lo(g3)+h2lo(g4)+h2lo(g5)+h2lo(g6)+h2lo(g7);
      float Ghi = h2hi(g0)+h2hi(g1)+h2hi(g2)+h2hi(g3)+h2hi(g4)+h2hi(g5)+h2hi(g6)+h2hi(g7);
      actL[b2][128 + j] = packh(cGL[b2]*Glo + cEL[b2]*Elo, cGL[b2]*Ghi + cEL[b2]*Ehi);
    }
  }
  __syncthreads();
  {
    int oo = tid>>3, kc = tid&7;
    int o = rk8*32 + oo;
    const float* wrow = P.outW + o*576 + kc*72;
    const unsigned* ab = &actL[bl_own][0];
    float p = 0.f;
    if (kc < 7){
      int u0 = 160 + kc*36;
      #pragma unroll 9
      for (int i = 0; i < 36; ++i){
        unsigned u = ab[u0+i];
        p += h2lo(u)*wrow[2*i] + h2hi(u)*wrow[2*i+1];
      }
    } else {
      #pragma unroll
      for (int i = 0; i < 4; ++i){
        unsigned u = ab[412+i];
        p += h2lo(u)*wrow[2*i] + h2hi(u)*wrow[2*i+1];
      }
      #pragma unroll 8
      for (int i = 0; i < 32; ++i){
        unsigned u = ab[128+i];
        p += h2lo(u)*wrow[8+2*i] + h2hi(u)*wrow[9+2*i];
      }
    }
    red[oo][kc] = p;
    __syncthreads();
    if (tid < 32){
      int o2 = rk8*32 + tid;
      float s = P.outb[o2];
      #pragma unroll
      for (int k2 = 0; k2 < 8; ++k2) s += red[tid][k2];
      P.out[((size_t)bglob*Sv + (Sv-1))*Ov + o2] = s;
    }
  }
  // ===== epilogue: final memory writeout =====
  for (int e2 = 0; e2 < 32; ++e2){
    int flat = tid + e2*256;
    int r = flat >> 6, v2 = flat & 63;
    P.memout[((size_t)bglob*Nv + (size_t)rk8*128 + r)*Vv + v2] = memL[r][v2];
  }
}

extern "C" void kernel_launch(void* const* d_in, const int* in_sizes, int n_in,
                              void* d_out, int out_size, void* d_ws, size_t ws_size,
                              hipStream_t stream) {
  (void)in_sizes; (void)n_in; (void)out_size; (void)ws_size;
  KP p;
  p.x       = (const float*)d_in[0];
  p.Wih     = (const float*)d_in[1];
  p.Whh     = (const float*)d_in[2];
  p.bih     = (const float*)d_in[3];
  p.bhh     = (const float*)d_in[4];
  p.rkW     = (const float*)d_in[5];  p.rkb     = (const float*)d_in[6];
  p.rsW     = (const float*)d_in[7];  p.rsb     = (const float*)d_in[8];
  p.rgW     = (const float*)d_in[9];  p.rgb     = (const float*)d_in[10];
  p.rgammaW = (const float*)d_in[13]; p.rgammab = (const float*)d_in[14];
  p.wkW     = (const float*)d_in[15]; p.wkb     = (const float*)d_in[16];
  p.wsW     = (const float*)d_in[17]; p.wsb     = (const float*)d_in[18];
  p.weW     = (const float*)d_in[19]; p.web     = (const float*)d_in[20];
  p.waW     = (const float*)d_in[21]; p.wab     = (const float*)d_in[22];
  p.outW    = (const float*)d_in[23]; p.outb    = (const float*)d_in[24];
  p.out     = (float*)d_out;
  p.memout  = (float*)d_out + (size_t)Bv*Sv*Ov;
  p.ws      = (float*)d_ws;

  hipMemsetAsync(d_ws, 0, ZERO_BYTES, stream);   // sync lines only (claim + GAL + XROOT)
  hipLaunchKernelGGL(ntm_kernel, dim3(NBLK), dim3(NTHR), 0, stream, p);
}

// Round 16
// 3970.575 us; speedup vs baseline: 1.4803x; 1.0690x over previous
//
#include <hip/hip_runtime.h>

#define Bv 32
#define Sv 256
#define Iv 256
#define Cv 512
#define Nv 1024
#define Vv 64
#define Ov 256
#define NBLK 256
#define NTHR 256

// ---- ws layout (int indices) ----
// sync region: host-memset each launch; sc1(agent)-only atomics/spins (proven incl. replays)
#define CLAIM_I(x)   ((x)*8)
#define GAL_I(x,q)   (64 + ((x)*4+(q))*8)
#define XROOT_I(x)   (320 + (x)*8)
#define ZERO_BYTES   (640*4)
// data region (never memset; single-XCD sc0 access; cross-step reads guarded at t==0)
#define FBASE 1024
#define HBU(x,t1,bb)  (FBASE + (x)*2048 + (t1)*1024 + (bb)*256)            // 256 uints: h f16x2
#define EGU(x,bb,k)   (FBASE + 16384 + (x)*2048 + (bb)*512 + (k)*64)      // 64 uints: E[32]|G[32] f16x2
#define SUMPF(x,bb,k) (FBASE + 32768 + (x)*128 + (bb)*32 + (k)*4)         // 4 floats: Se,Sg,Sw,gate
#define HPF(x,bb,r)   (FBASE + 33792 + (((x)*4+(bb))*32 + (r))*264)       // 264 floats: head partials

struct KP {
  const float *x, *Wih, *Whh, *bih, *bhh;
  const float *rkW, *rkb, *rsW, *rsb, *rgW, *rgb, *rgammaW, *rgammab;
  const float *wkW, *wkb, *wsW, *wsb, *weW, *web, *waW, *wab;
  const float *outW, *outb;
  float *out;
  float *memout;
  float *ws;
};

typedef _Float16 half2v __attribute__((ext_vector_type(2)));
union HU { unsigned u; half2v h; };

__device__ inline float sigf(float x){ return 1.f/(1.f+expf(-x)); }
__device__ inline float softplusf(float x){ return fmaxf(x,0.f) + log1pf(expf(-fabsf(x))); }
__device__ inline unsigned packh(float a, float b){
  HU z; z.h = half2v{(_Float16)a, (_Float16)b}; return z.u;
}
__device__ inline float h2lo(unsigned u){ HU z; z.u = u; return (float)z.h.x; }
__device__ inline float h2hi(unsigned u){ HU z; z.u = u; return (float)z.h.y; }
__device__ inline float dot2(unsigned w, unsigned a, float acc){
  HU wu, au; wu.u = w; au.u = a;
  return __builtin_amdgcn_fdot2(wu.h, au.h, acc, false);
}

// ---- sc0 (XCD-L2-local) DATA access (proven: single-XCD, sc1-barrier-ordered) ----
__device__ inline void stg_f(float* p, float v){
  asm volatile("global_store_dword %0, %1, off sc0" :: "v"(p), "v"(v) : "memory");
}
__device__ inline void stg_u(unsigned* p, unsigned v){
  asm volatile("global_store_dword %0, %1, off sc0" :: "v"(p), "v"(v) : "memory");
}
#define LDG4U(dst, addr) asm volatile("global_load_dwordx4 %0, %1, off sc0" : "=v"(dst) : "v"(addr) : "memory")
#define LDG4F(dst, addr) asm volatile("global_load_dwordx4 %0, %1, off sc0" : "=v"(dst) : "v"(addr) : "memory")
#define LDGU(dst, addr)  asm volatile("global_load_dword %0, %1, off sc0"  : "=v"(dst) : "v"(addr) : "memory")
#define LDGF(dst, addr)  asm volatile("global_load_dword %0, %1, off sc0"  : "=v"(dst) : "v"(addr) : "memory")
#define WAITV do { asm volatile("s_waitcnt vmcnt(0)" ::: "memory"); __builtin_amdgcn_sched_barrier(0); } while(0)

// ---- sc1 (agent/MALL) SYNC ops on memset lines (proven incl. replays) ----
#define AADD(p,v) __hip_atomic_fetch_add((p),(v),__ATOMIC_RELAXED,__HIP_MEMORY_SCOPE_AGENT)
#define ALD(p)    __hip_atomic_load((p),__ATOMIC_RELAXED,__HIP_MEMORY_SCOPE_AGENT)

#define SPIN(cond_expr) do { unsigned sp = 0; \
  while (cond_expr){ __builtin_amdgcn_s_sleep(2); \
    if (((++sp)&1023u)==0u && (__builtin_amdgcn_s_memrealtime()-t0) > 300000000ULL) break; } } while(0)

__device__ inline float headact(int o, float s){
  if (o < 64)  return tanhf(s);
  if (o == 64) return softplusf(s);
  if (o == 65) return sigf(s);
  if (o == 66) return 1.f + softplusf(s);
  if (o < 131) return tanhf(s);
  if (o == 131) return softplusf(s);
  if (o < 196) return sigf(s);
  return tanhf(s);
}
__device__ inline void head_src(const KP& P, int o, const float** row, float* bias){
  if (o < 64)       { *row = P.rkW + o*Cv;        *bias = P.rkb[o]; }
  else if (o == 64) { *row = P.rsW;               *bias = P.rsb[0]; }
  else if (o == 65) { *row = P.rgW;               *bias = P.rgb[0]; }
  else if (o == 66) { *row = P.rgammaW;           *bias = P.rgammab[0]; }
  else if (o < 131) { *row = P.wkW + (o-67)*Cv;   *bias = P.wkb[o-67]; }
  else if (o == 131){ *row = P.wsW;               *bias = P.wsb[0]; }
  else if (o < 196) { *row = P.weW + (o-132)*Cv;  *bias = P.web[o-132]; }
  else              { *row = P.waW + (o-196)*Cv;  *bias = P.wab[o-196]; }
}

__global__ __launch_bounds__(NTHR) void ntm_kernel(KP P){
  __shared__ unsigned actL[4][420];   // [x(128)|rv(32)|h(256)] f16 pairs per local batch
  __shared__ float memL[128][66];
  __shared__ float gbq[4][4][68];     // GEMM quarter-partials [q][batch][row]
  __shared__ float biasL[64];
  __shared__ float htmpf[16][5];
  __shared__ float headsL[264];
  __shared__ float pendE[64], pendA[64];   // pending erase/add (deferred mem update)
  __shared__ float knr[64], knw[64];
  __shared__ float scal[8];
  __shared__ float erL2[128], egL2[128], ewL[128];
  __shared__ float red[32][9];
  __shared__ float red2[2][4];
  __shared__ float sumS1[4][8][4];
  __shared__ float cEL[4], cGL[4];
  __shared__ float rvpE[4][64], rvpG[4][64];
  __shared__ float rvfinE[64], rvfinG[64];
  __shared__ int sXcd, sRank;

  const int tid = threadIdx.x;
  float* wsf = P.ws;
  unsigned* wsu = (unsigned*)P.ws;
  int* wsi = (int*)P.ws;
  const unsigned long long t0 = __builtin_amdgcn_s_memrealtime();

  // ---- XCD discovery + rank claim (sc1 on memset line) ----
  if (tid == 0){
    unsigned xcc;
    asm volatile("s_getreg_b32 %0, hwreg(20, 0, 32)" : "=s"(xcc));  // HW_REG_XCC_ID
    int xc = (int)(xcc & 7u);
    int rk = AADD(&wsi[CLAIM_I(xc)], 1);
    sXcd = xc; sRank = rk & 31;
  }
  __syncthreads();
  const int xcd = sXcd, rank = sRank;
  const int bl_own = rank >> 3;
  const int rk8 = rank & 7;
  const int bglob = xcd*4 + bl_own;

  // ---- startup: gate W (f16) into VGPRs; bias; head slices ----
  const int qw = tid >> 6;            // column-quarter (= wave id)
  const int rw = tid & 63;            // gate-row within block
  const int grw = (rw>>4)*Cv + rank*16 + (rw&15);
  uint4 wreg[26];
  {
    #pragma unroll
    for (int jj = 0; jj < 26; ++jj){
      unsigned uu[4];
      #pragma unroll
      for (int c = 0; c < 4; ++c){
        int e = qw*208 + 8*jj + 2*c;
        float2 w2;
        if (e < 320) w2 = *(const float2*)(P.Wih + grw*320 + e);
        else         w2 = *(const float2*)(P.Whh + grw*512 + (e-320));
        uu[c] = packh(w2.x, w2.y);
      }
      wreg[jj].x = uu[0]; wreg[jj].y = uu[1]; wreg[jj].z = uu[2]; wreg[jj].w = uu[3];
    }
  }
  if (tid < 64){
    int gr = (tid>>4)*Cv + rank*16 + (tid&15);
    biasL[tid] = P.bih[gr] + P.bhh[gr];
  }
  float wA[16], wB[16], bA = 0.f, bB = 0.f;
  {
    const float* rowA; head_src(P, tid, &rowA, &bA);
    #pragma unroll
    for (int j = 0; j < 16; ++j) wA[j] = rowA[rank*16 + j];
    const float* rowB; head_src(P, 256 + (tid & 3), &rowB, &bB);
    #pragma unroll
    for (int j = 0; j < 16; ++j) wB[j] = rowB[rank*16 + j];
  }
  for (int idx = tid; idx < 128*66; idx += NTHR) ((float*)memL)[idx] = 0.f;
  __syncthreads();

  float cS = 0.f;                      // LSTM cell state (tid<64: (j,bb))
  int gs = 0;
  const int sbb = tid>>6, spart = tid&63;  // staging mapping
  float4 xv;                            // x(t) staged across barrier
  uint4 hq = {};                        // h(t-1) staged across barrier
  xv = *(const float4*)(P.x + ((size_t)(xcd*4+sbb)*Sv + 0)*Iv + spart*4);  // prologue x(0)

  for (int t = 0; t < Sv; ++t){
    // ===== S1: consume staging; rv combine; pending mem update; GEMM; c/h; h store; HP; XB-A; outproj(t-1) =====
    if (t > 0){
      unsigned e0,e1,e2,e3,e4,e5,e6,e7,g0,g1,g2,g3,g4,g5,g6,g7;
      float4 sv = {0,0,0,0};
      int b2 = tid>>5, j = tid&31;
      if (tid < 128){
        const unsigned* eb = wsu + EGU(xcd,b2,0) + j;
        LDGU(e0,eb+0*64); LDGU(e1,eb+1*64); LDGU(e2,eb+2*64); LDGU(e3,eb+3*64);
        LDGU(e4,eb+4*64); LDGU(e5,eb+5*64); LDGU(e6,eb+6*64); LDGU(e7,eb+7*64);
        const unsigned* ggb = eb + 32;
        LDGU(g0,ggb+0*64); LDGU(g1,ggb+1*64); LDGU(g2,ggb+2*64); LDGU(g3,ggb+3*64);
        LDGU(g4,ggb+4*64); LDGU(g5,ggb+5*64); LDGU(g6,ggb+6*64); LDGU(g7,ggb+7*64);
      }
      if (tid < 32){ LDG4F(sv, wsf + SUMPF(xcd, tid>>3, tid&7)); }
      WAITV;                         // drains EGU/SUMPF + staged hq (+x handled by compiler)
      actL[sbb][spart*2]   = packh(xv.x, xv.y);
      actL[sbb][spart*2+1] = packh(xv.z, xv.w);
      *(uint4*)&actL[sbb][160 + spart*4] = hq;
      if (tid < 32) *(float4*)&sumS1[tid>>3][tid&7][0] = sv;
      __syncthreads();
      if (tid < 4){
        float Se = 0.f, Sg = 0.f;
        #pragma unroll
        for (int k2 = 0; k2 < 8; ++k2){ Se += sumS1[tid][k2][0]; Sg += sumS1[tid][k2][1]; }
        float g = sumS1[tid][0][3];
        cEL[tid] = (1.f - g)/Se;
        cGL[tid] = g/Sg;
      }
      if (tid == 0){
        float Sw = 0.f;
        #pragma unroll
        for (int k2 = 0; k2 < 8; ++k2) Sw += sumS1[0][k2][2] + sumS1[1][k2][2] + sumS1[2][k2][2] + sumS1[3][k2][2];
        // NOTE: Sw must sum only own-batch partials! sumS1[bb][k][2] is per-batch.
        scal[6] = 0.f; // placeholder (overwritten below)
      }
      __syncthreads();
      if (tid == 0){
        float Sw = 0.f;
        #pragma unroll
        for (int k2 = 0; k2 < 8; ++k2) Sw += sumS1[bl_own][k2][2];
        scal[6] = Sw;
      }
      if (tid < 128){
        float Elo = h2lo(e0)+h2lo(e1)+h2lo(e2)+h2lo(e3)+h2lo(e4)+h2lo(e5)+h2lo(e6)+h2lo(e7);
        float Ehi = h2hi(e0)+h2hi(e1)+h2hi(e2)+h2hi(e3)+h2hi(e4)+h2hi(e5)+h2hi(e6)+h2hi(e7);
        float Glo = h2lo(g0)+h2lo(g1)+h2lo(g2)+h2lo(g3)+h2lo(g4)+h2lo(g5)+h2lo(g6)+h2lo(g7);
        float Ghi = h2hi(g0)+h2hi(g1)+h2hi(g2)+h2hi(g3)+h2hi(g4)+h2hi(g5)+h2hi(g6)+h2hi(g7);
        actL[b2][128 + j] = packh(cGL[b2]*Glo + cEL[b2]*Elo, cGL[b2]*Ghi + cEL[b2]*Ehi);
      }
      __syncthreads();
      {  // deferred memory update (step t-1): uses ewL(t-1), pendE/pendA(t-1), Sw(t-1)
        float rSw = 1.f/scal[6];
        #pragma unroll 4
        for (int e9 = 0; e9 < 32; ++e9){
          int flat = tid + e9*256;
          int r = flat >> 6, v2 = flat & 63;
          float ww = ewL[r]*rSw;
          memL[r][v2] = memL[r][v2]*(1.f - ww*pendE[v2]) + ww*pendA[v2];
        }
      }
    } else {
      actL[sbb][spart*2]   = packh(xv.x, xv.y);
      actL[sbb][spart*2+1] = packh(xv.z, xv.w);
      for (int idx = tid; idx < 4*288; idx += NTHR){
        int bb2 = idx/288, u = 128 + idx%288;
        actL[bb2][u] = 0u;
      }
    }
    __syncthreads();
    {  // gate GEMM: weights in VGPRs, activations broadcast from LDS
      const int base0 = qw*104;
      float a00=0.f,a01=0.f,a10=0.f,a11=0.f,a20=0.f,a21=0.f,a30=0.f,a31=0.f;
      #pragma unroll
      for (int jj = 0; jj < 26; ++jj){
        uint4 w = wreg[jj];
        uint4 v0 = *(const uint4*)&actL[0][base0+4*jj];
        uint4 v1 = *(const uint4*)&actL[1][base0+4*jj];
        uint4 v2 = *(const uint4*)&actL[2][base0+4*jj];
        uint4 v3 = *(const uint4*)&actL[3][base0+4*jj];
        a00=dot2(w.x,v0.x,a00); a01=dot2(w.y,v0.y,a01); a00=dot2(w.z,v0.z,a00); a01=dot2(w.w,v0.w,a01);
        a10=dot2(w.x,v1.x,a10); a11=dot2(w.y,v1.y,a11); a10=dot2(w.z,v1.z,a10); a11=dot2(w.w,v1.w,a11);
        a20=dot2(w.x,v2.x,a20); a21=dot2(w.y,v2.y,a21); a20=dot2(w.z,v2.z,a20); a21=dot2(w.w,v2.w,a21);
        a30=dot2(w.x,v3.x,a30); a31=dot2(w.y,v3.y,a31); a30=dot2(w.z,v3.z,a30); a31=dot2(w.w,v3.w,a31);
      }
      gbq[qw][0][rw] = a00+a01;
      gbq[qw][1][rw] = a10+a11;
      gbq[qw][2][rw] = a20+a21;
      gbq[qw][3][rw] = a30+a31;
    }
    __syncthreads();
    if (tid < 64){
      int j = tid>>2, bb = tid&3;
      float ig = biasL[j]    + gbq[0][bb][j]    + gbq[1][bb][j]    + gbq[2][bb][j]    + gbq[3][bb][j];
      float fg = biasL[16+j] + gbq[0][bb][16+j] + gbq[1][bb][16+j] + gbq[2][bb][16+j] + gbq[3][bb][16+j];
      float gg = biasL[32+j] + gbq[0][bb][32+j] + gbq[1][bb][32+j] + gbq[2][bb][32+j] + gbq[3][bb][32+j];
      float og = biasL[48+j] + gbq[0][bb][48+j] + gbq[1][bb][48+j] + gbq[2][bb][48+j] + gbq[3][bb][48+j];
      cS = sigf(fg)*cS + sigf(ig)*tanhf(gg);
      htmpf[j][bb] = sigf(og)*tanhf(cS);
    }
    __syncthreads();
    if (tid < 32){
      int pr = tid>>2, bb = tid&3;
      stg_u(wsu + HBU(xcd,t&1,bb) + rank*8 + pr, packh(htmpf[2*pr][bb], htmpf[2*pr+1][bb]));
    }
    {  // head partials over own 16 channels, all 260 outputs x 4 batches
      float p0=0.f,p1=0.f,p2=0.f,p3=0.f,q0=0.f,q1=0.f,q2=0.f,q3=0.f;
      #pragma unroll
      for (int j = 0; j < 16; ++j){
        float h0=htmpf[j][0], h1=htmpf[j][1], h2=htmpf[j][2], h3=htmpf[j][3];
        p0+=wA[j]*h0; p1+=wA[j]*h1; p2+=wA[j]*h2; p3+=wA[j]*h3;
        q0+=wB[j]*h0; q1+=wB[j]*h1; q2+=wB[j]*h2; q3+=wB[j]*h3;
      }
      stg_f(wsf + HPF(xcd,0,rank) + tid, p0);
      stg_f(wsf + HPF(xcd,1,rank) + tid, p1);
      stg_f(wsf + HPF(xcd,2,rank) + tid, p2);
      stg_f(wsf + HPF(xcd,3,rank) + tid, p3);
      if (tid < 4){
        int o2 = 256 + tid;
        stg_f(wsf + HPF(xcd,0,rank) + o2, q0);
        stg_f(wsf + HPF(xcd,1,rank) + o2, q1);
        stg_f(wsf + HPF(xcd,2,rank) + o2, q2);
        stg_f(wsf + HPF(xcd,3,rank) + o2, q3);
      }
    }
    // XB-A arrive (32-wide tree, sc1)
    WAITV;
    __syncthreads();
    if (tid == 0){
      int a = AADD(&wsi[GAL_I(xcd, rank>>3)], 1);
      if (a == 8*(gs+1) - 1) AADD(&wsi[XROOT_I(xcd)], 1);
    }
    if (t > 0){  // out-proj(t-1), hidden under XB-A
      int oo = tid>>3, kc = tid&7;
      int o = rk8*32 + oo;
      const float* wrow = P.outW + o*576 + kc*72;
      const unsigned* ab = &actL[bl_own][0];
      float p = 0.f;
      if (kc < 7){
        int u0 = 160 + kc*36;
        #pragma unroll 9
        for (int i = 0; i < 36; ++i){
          unsigned u = ab[u0+i];
          p += h2lo(u)*wrow[2*i] + h2hi(u)*wrow[2*i+1];
        }
      } else {
        #pragma unroll
        for (int i = 0; i < 4; ++i){
          unsigned u = ab[412+i];
          p += h2lo(u)*wrow[2*i] + h2hi(u)*wrow[2*i+1];
        }
        #pragma unroll 8
        for (int i = 0; i < 32; ++i){
          unsigned u = ab[128+i];
          p += h2lo(u)*wrow[8+2*i] + h2hi(u)*wrow[9+2*i];
        }
      }
      red[oo][kc] = p;
      __syncthreads();
      if (tid < 32){
        int o2 = rk8*32 + tid;
        float s = P.outb[o2];
        #pragma unroll
        for (int k2 = 0; k2 < 8; ++k2) s += red[tid][k2];
        P.out[((size_t)bglob*Sv + (t-1))*Ov + o2] = s;
      }
    }
    if (tid == 0){ SPIN(ALD(&wsi[XROOT_I(xcd)]) < 4*(gs+1)); }
    __syncthreads();
    ++gs;

    // ===== S2': head reduce (own batch, 2 round trips); content addressing; sums+E/G; XB-B =====
    {
      float s = bA, s2 = bB;
      #pragma unroll
      for (int half = 0; half < 2; ++half){
        const float* hb = wsf + HPF(xcd, bl_own, half*16);
        float av[16], bv[16];
        #pragma unroll
        for (int i = 0; i < 16; ++i){ LDGF(av[i], hb + i*264 + tid); }
        if (tid < 4){
          #pragma unroll
          for (int i = 0; i < 16; ++i){ LDGF(bv[i], hb + i*264 + 256 + tid); }
        }
        WAITV;
        #pragma unroll
        for (int i = 0; i < 16; ++i) s += av[i];
        if (tid < 4){
          #pragma unroll
          for (int i = 0; i < 16; ++i) s2 += bv[i];
        }
      }
      float hv = headact(tid, s);
      headsL[tid] = hv;
      if (tid >= 132 && tid < 196) pendE[tid-132] = hv;
      if (tid >= 196) pendA[tid-196] = hv;
      if (tid < 4){
        float hv2 = headact(256+tid, s2);
        headsL[256+tid] = hv2;
        pendA[60+tid] = hv2;
      }
    }
    __syncthreads();
    if (tid < 64){
      float kr = headsL[tid], kw = headsL[67+tid];
      float sr = kr*kr, sw2 = kw*kw;
      #pragma unroll
      for (int off = 32; off; off >>= 1){ sr += __shfl_xor(sr, off); sw2 += __shfl_xor(sw2, off); }
      knr[tid] = kr * (1.f/fmaxf(sqrtf(sr), 1e-12f));
      knw[tid] = kw * (1.f/fmaxf(sqrtf(sw2), 1e-12f));
    }
    __syncthreads();
    {
      float str_r = headsL[64], gamma = headsL[66], str_w = headsL[131];
      float er = 0.f, eg = 0.f, ew = 0.f;
      if (tid < 128){
        float dr = 0.f, dw = 0.f, nn = 0.f;
        #pragma unroll 8
        for (int v = 0; v < 64; ++v){
          float m = memL[tid][v];
          dr += m*knr[v]; dw += m*knw[v]; nn += m*m;
        }
        float innm = 1.f/fmaxf(sqrtf(nn), 1e-12f);
        float tr = str_r*(dr*innm - 1.f);
        er = expf(tr);
        eg = expf(gamma*tr);
        ew = expf(str_w*(dw*innm - 1.f));
        erL2[tid] = er; egL2[tid] = eg; ewL[tid] = ew;
      }
      float s0 = er, s1 = eg, s2 = ew;
      #pragma unroll
      for (int off = 32; off; off >>= 1){
        s0 += __shfl_xor(s0, off); s1 += __shfl_xor(s1, off); s2 += __shfl_xor(s2, off);
      }
      if ((tid & 63) == 0 && tid < 128){
        int wv = tid>>6; red2[wv][0] = s0; red2[wv][1] = s1; red2[wv][2] = s2;
      }
      __syncthreads();
      if (tid == 0){
        float* sp = wsf + SUMPF(xcd,bl_own,rk8);
        stg_f(sp+0, red2[0][0]+red2[1][0]);
        stg_f(sp+1, red2[0][1]+red2[1][1]);
        stg_f(sp+2, red2[0][2]+red2[1][2]);
        stg_f(sp+3, headsL[65]);
      }
    }
    // unnormalized E/G partials on current (post-update(t-1)) memory
    {
      int v = tid & 63, cc = tid >> 6;
      float pE = 0.f, pG = 0.f;
      #pragma unroll 8
      for (int j = 0; j < 32; ++j){
        int r = cc*32 + j;
        float m = memL[r][v];
        pE += erL2[r]*m; pG += egL2[r]*m;
      }
      rvpE[cc][v] = pE; rvpG[cc][v] = pG;
    }
    __syncthreads();
    if (tid < 64){
      rvfinE[tid] = rvpE[0][tid]+rvpE[1][tid]+rvpE[2][tid]+rvpE[3][tid];
      rvfinG[tid] = rvpG[0][tid]+rvpG[1][tid]+rvpG[2][tid]+rvpG[3][tid];
    }
    __syncthreads();
    if (tid < 32)
      stg_u(wsu + EGU(xcd,bl_own,rk8) + tid, packh(rvfinE[2*tid], rvfinE[2*tid+1]));
    else if (tid < 64)
      stg_u(wsu + EGU(xcd,bl_own,rk8) + tid, packh(rvfinG[2*(tid-32)], rvfinG[2*(tid-32)+1]));
    // XB-B (32-wide tree, sc1): arrive, prefetch next staging under spin, wait
    WAITV;
    __syncthreads();
    if (tid == 0){
      int a = AADD(&wsi[GAL_I(xcd, rank>>3)], 1);
      if (a == 8*(gs+1) - 1) AADD(&wsi[XROOT_I(xcd)], 1);
    }
    {
      if (t + 1 < Sv)
        xv = *(const float4*)(P.x + ((size_t)(xcd*4+sbb)*Sv + (size_t)(t+1))*Iv + spart*4);
      LDG4U(hq, wsu + HBU(xcd, t&1, sbb) + spart*4);   // h(t), visible since XB-A(t)
    }
    if (tid == 0){ SPIN(ALD(&wsi[XROOT_I(xcd)]) < 4*(gs+1)); }
    __syncthreads();
    ++gs;
  }

  // ===== epilogue: consume staging; final pending update; out-proj(S-1); memout =====
  {
    unsigned e0,e1,e2,e3,e4,e5,e6,e7,g0,g1,g2,g3,g4,g5,g6,g7;
    float4 sv = {0,0,0,0};
    int b2 = tid>>5, j = tid&31;
    if (tid < 128){
      const unsigned* eb = wsu + EGU(xcd,b2,0) + j;
      LDGU(e0,eb+0*64); LDGU(e1,eb+1*64); LDGU(e2,eb+2*64); LDGU(e3,eb+3*64);
      LDGU(e4,eb+4*64); LDGU(e5,eb+5*64); LDGU(e6,eb+6*64); LDGU(e7,eb+7*64);
      const unsigned* ggb = eb + 32;
      LDGU(g0,ggb+0*64); LDGU(g1,ggb+1*64); LDGU(g2,ggb+2*64); LDGU(g3,ggb+3*64);
      LDGU(g4,ggb+4*64); LDGU(g5,ggb+5*64); LDGU(g6,ggb+6*64); LDGU(g7,ggb+7*64);
    }
    if (tid < 32){ LDG4F(sv, wsf + SUMPF(xcd, tid>>3, tid&7)); }
    WAITV;
    *(uint4*)&actL[sbb][160 + spart*4] = hq;
    if (tid < 32) *(float4*)&sumS1[tid>>3][tid&7][0] = sv;
    __syncthreads();
    if (tid < 4){
      float Se = 0.f, Sg = 0.f;
      #pragma unroll
      for (int k2 = 0; k2 < 8; ++k2){ Se += sumS1[tid][k2][0]; Sg += sumS1[tid][k2][1]; }
      float g = sumS1[tid][0][3];
      cEL[tid] = (1.f - g)/Se;
      cGL[tid] = g/Sg;
    }
    if (tid == 0){
      float Sw = 0.f;
      #pragma unroll
      for (int k2 = 0; k2 < 8; ++k2) Sw += sumS1[bl_own][k2][2];
      scal[6] = Sw;
    }
    __syncthreads();
    if (tid < 128){
      float Elo = h2lo(e0)+h2lo(e1)+h2lo(e2)+h2lo(e3)+h2lo(e4)+h2lo(e5)+h2lo(e6)+h2lo(e7);
      float Ehi = h2hi(e0)+h2hi(e1)+h2hi(e2)+h2hi(e3)+h2hi(e4)+h2hi(e5)+h2hi(e6)+h2hi(e7);
      float Glo = h2lo(g0)+h2lo(g1)+h2lo(g2)+h2lo(g3)+h2lo(g4)+h2lo(g5)+h2lo(g6)+h2lo(g7);
      float Ghi = h2hi(g0)+h2hi(g1)+h2hi(g2)+h2hi(g3)+h2hi(g4)+h2hi(g5)+h2hi(g6)+h2hi(g7);
      actL[b2][128 + j] = packh(cGL[b2]*Glo + cEL[b2]*Elo, cGL[b2]*Ghi + cEL[b2]*Ehi);
    }
    __syncthreads();
    {  // final pending update (step S-1)
      float rSw = 1.f/scal[6];
      #pragma unroll 4
      for (int e9 = 0; e9 < 32; ++e9){
        int flat = tid + e9*256;
        int r = flat >> 6, v2 = flat & 63;
        float ww = ewL[r]*rSw;
        memL[r][v2] = memL[r][v2]*(1.f - ww*pendE[v2]) + ww*pendA[v2];
      }
    }
    __syncthreads();
  }
  {
    int oo = tid>>3, kc = tid&7;
    int o = rk8*32 + oo;
    const float* wrow = P.outW + o*576 + kc*72;
    const unsigned* ab = &actL[bl_own][0];
    float p = 0.f;
    if (kc < 7){
      int u0 = 160 + kc*36;
      #pragma unroll 9
      for (int i = 0; i < 36; ++i){
        unsigned u = ab[u0+i];
        p += h2lo(u)*wrow[2*i] + h2hi(u)*wrow[2*i+1];
      }
    } else {
      #pragma unroll
      for (int i = 0; i < 4; ++i){
        unsigned u = ab[412+i];
        p += h2lo(u)*wrow[2*i] + h2hi(u)*wrow[2*i+1];
      }
      #pragma unroll 8
      for (int i = 0; i < 32; ++i){
        unsigned u = ab[128+i];
        p += h2lo(u)*wrow[8+2*i] + h2hi(u)*wrow[9+2*i];
      }
    }
    red[oo][kc] = p;
    __syncthreads();
    if (tid < 32){
      int o2 = rk8*32 + tid;
      float s = P.outb[o2];
      #pragma unroll
      for (int k2 = 0; k2 < 8; ++k2) s += red[tid][k2];
      P.out[((size_t)bglob*Sv + (Sv-1))*Ov + o2] = s;
    }
  }
  // ===== epilogue: final memory writeout =====
  for (int e9 = 0; e9 < 32; ++e9){
    int flat = tid + e9*256;
    int r = flat >> 6, v2 = flat & 63;
    P.memout[((size_t)bglob*Nv + (size_t)rk8*128 + r)*Vv + v2] = memL[r][v2];
  }
}

extern "C" void kernel_launch(void* const* d_in, const int* in_sizes, int n_in,
                              void* d_out, int out_size, void* d_ws, size_t ws_size,
                              hipStream_t stream) {
  (void)in_sizes; (void)n_in; (void)out_size; (void)ws_size;
  KP p;
  p.x       = (const float*)d_in[0];
  p.Wih     = (const float*)d_in[1];
  p.Whh     = (const float*)d_in[2];
  p.bih     = (const float*)d_in[3];
  p.bhh     = (const float*)d_in[4];
  p.rkW     = (const float*)d_in[5];  p.rkb     = (const float*)d_in[6];
  p.rsW     = (const float*)d_in[7];  p.rsb     = (const float*)d_in[8];
  p.rgW     = (const float*)d_in[9];  p.rgb     = (const float*)d_in[10];
  p.rgammaW = (const float*)d_in[13]; p.rgammab = (const float*)d_in[14];
  p.wkW     = (const float*)d_in[15]; p.wkb     = (const float*)d_in[16];
  p.wsW     = (const float*)d_in[17]; p.wsb     = (const float*)d_in[18];
  p.weW     = (const float*)d_in[19]; p.web     = (const float*)d_in[20];
  p.waW     = (const float*)d_in[21]; p.wab     = (const float*)d_in[22];
  p.outW    = (const float*)d_in[23]; p.outb    = (const float*)d_in[24];
  p.out     = (float*)d_out;
  p.memout  = (float*)d_out + (size_t)Bv*Sv*Ov;
  p.ws      = (float*)d_ws;

  hipMemsetAsync(d_ws, 0, ZERO_BYTES, stream);   // sync lines only (claim + GAL + XROOT)
  hipLaunchKernelGGL(ntm_kernel, dim3(NBLK), dim3(NTHR), 0, stream, p);
}